// Round 1
// baseline (596.422 us; speedup 1.0000x reference)
//
#include <hip/hip_runtime.h>
#include <math.h>

// Problem constants
constexpr int Bc  = 16;
constexpr int Cch = 256;
constexpr int Gc  = 8;
constexpr int CGc = 32;    // C/G
constexpr int Nc  = 1024;  // H*W
constexpr float EPSc = 1e-5f;
constexpr float SCc  = 0.125f; // dh^-0.5, dh=64

// ---------------------------------------------------------------------------
// Kernel 1: per-(b,g) mean / invstd.  Grid = B*G = 128 blocks.
// ---------------------------------------------------------------------------
__global__ __launch_bounds__(256) void gn_stats_k(const float* __restrict__ x,
                                                  float* __restrict__ stats) {
    int bg = blockIdx.x;  // b*G + g ; channels of a group are contiguous
    const float* p = x + (size_t)bg * (CGc * Nc);
    float s = 0.f, s2 = 0.f;
    for (int i = threadIdx.x; i < CGc * Nc; i += 256) {
        float v = p[i];
        s += v; s2 += v * v;
    }
    __shared__ float rs[256], rq[256];
    rs[threadIdx.x] = s; rq[threadIdx.x] = s2;
    __syncthreads();
    for (int off = 128; off > 0; off >>= 1) {
        if (threadIdx.x < (unsigned)off) {
            rs[threadIdx.x] += rs[threadIdx.x + off];
            rq[threadIdx.x] += rq[threadIdx.x + off];
        }
        __syncthreads();
    }
    if (threadIdx.x == 0) {
        float inv_n = 1.f / (float)(CGc * Nc);
        float mean = rs[0] * inv_n;
        float var  = rq[0] * inv_n - mean * mean;
        stats[bg * 2]     = mean;
        stats[bg * 2 + 1] = rsqrtf(var + EPSc);
    }
}

// ---------------------------------------------------------------------------
// Kernel 2: qkv = qkv_w (768x256) @ groupnorm(x)(256x1024) + qkv_b, per batch.
// GroupNorm applied on the fly while staging the B tile.
// Grid: (n_tiles=16, m_tiles=12, B=16); 256 thr; 64x64x64 tiles, 4x4 micro.
// ---------------------------------------------------------------------------
__global__ __launch_bounds__(256) void qkv_gemm_k(
    const float* __restrict__ x, const float* __restrict__ stats,
    const float* __restrict__ nw, const float* __restrict__ nb,
    const float* __restrict__ w, const float* __restrict__ wb,
    float* __restrict__ out) {
    int b  = blockIdx.z;
    int m0 = blockIdx.y * 64;
    int n0 = blockIdx.x * 64;
    __shared__ __align__(16) float As[64][68]; // [k][m]  (transposed for b128 reads)
    __shared__ __align__(16) float Bs[64][68]; // [k][n]
    int t = threadIdx.x, ty = t >> 4, tx = t & 15;
    float acc[4][4] = {};
    for (int k0 = 0; k0 < 256; k0 += 64) {
        __syncthreads();
#pragma unroll
        for (int r = 0; r < 16; r++) {
            int e = t + r * 256;
            int k = e & 63, m = e >> 6;
            As[k][m] = w[(m0 + m) * 256 + k0 + k];
        }
#pragma unroll
        for (int r = 0; r < 16; r++) {
            int e = t + r * 256;
            int n = e & 63, k = e >> 6;
            int c = k0 + k;
            int g = c >> 5;
            float mean = stats[(b * Gc + g) * 2];
            float inv  = stats[(b * Gc + g) * 2 + 1];
            float v = x[((size_t)(b * Cch + c)) * Nc + n0 + n];
            Bs[k][n] = (v - mean) * inv * nw[c] + nb[c];
        }
        __syncthreads();
#pragma unroll 16
        for (int k = 0; k < 64; k++) {
            float4 av = *(const float4*)&As[k][ty * 4];
            float4 bv = *(const float4*)&Bs[k][tx * 4];
            float a4[4] = {av.x, av.y, av.z, av.w};
            float b4[4] = {bv.x, bv.y, bv.z, bv.w};
#pragma unroll
            for (int i = 0; i < 4; i++)
#pragma unroll
                for (int j = 0; j < 4; j++) acc[i][j] += a4[i] * b4[j];
        }
    }
#pragma unroll
    for (int i = 0; i < 4; i++) {
        int m = m0 + ty * 4 + i;
        float bb = wb[m];
        float4 r4;
        r4.x = acc[i][0] + bb; r4.y = acc[i][1] + bb;
        r4.z = acc[i][2] + bb; r4.w = acc[i][3] + bb;
        *(float4*)&out[((size_t)(b * 768 + m)) * Nc + n0 + tx * 4] = r4;
    }
}

// ---------------------------------------------------------------------------
// Kernel 3: flash-style attention per (b,h,i-tile).
// S tile 64x64 in LDS, online softmax, O accumulated in registers.
// Grid: (i_tiles=16, B*NH=64); 256 thr.
// ---------------------------------------------------------------------------
__global__ __launch_bounds__(256) void attn_k(const float* __restrict__ qkv,
                                              float* __restrict__ ob) {
    int i0 = blockIdx.x * 64;
    int bh = blockIdx.y;
    int b = bh >> 2, h = bh & 3;
    const float* qb = qkv + ((size_t)(b * 768 + h * 64)) * Nc;
    const float* kb = qb + (size_t)256 * Nc;
    const float* vb = qb + (size_t)512 * Nc;
    __shared__ __align__(16) float Qs[64][68]; // [c][i]
    __shared__ __align__(16) float Ks[64][68]; // [c][j]
    __shared__ __align__(16) float Vt[64][68]; // [j][c]
    __shared__ float Ss[64][65];               // [i][j] -> P after softmax
    __shared__ float mrow[64], lrow[64], arow[64];
    __shared__ float pm[64][4], ps[64][4];
    int t = threadIdx.x, ty = t >> 4, tx = t & 15;
#pragma unroll
    for (int r = 0; r < 16; r++) {
        int e = t + r * 256;
        int i = e & 63, c = e >> 6;
        Qs[c][i] = qb[(size_t)c * Nc + i0 + i];
    }
    if (t < 64) { mrow[t] = -1e30f; lrow[t] = 0.f; }
    float oacc[4][4] = {}; // [cc][ii], c = ty*4+cc, i = tx*4+ii
    for (int j0 = 0; j0 < Nc; j0 += 64) {
        __syncthreads();
#pragma unroll
        for (int r = 0; r < 16; r++) {
            int e = t + r * 256;
            int j = e & 63, c = e >> 6;
            Ks[c][j] = kb[(size_t)c * Nc + j0 + j];
            Vt[j][c] = vb[(size_t)c * Nc + j0 + j];
        }
        __syncthreads();
        // ---- S = sc * Q^T K  (i x j) ----
        float sacc[4][4] = {};
#pragma unroll 16
        for (int c = 0; c < 64; c++) {
            float4 qv = *(const float4*)&Qs[c][ty * 4];
            float4 kv = *(const float4*)&Ks[c][tx * 4];
            float a4[4] = {qv.x, qv.y, qv.z, qv.w};
            float b4[4] = {kv.x, kv.y, kv.z, kv.w};
#pragma unroll
            for (int i = 0; i < 4; i++)
#pragma unroll
                for (int j = 0; j < 4; j++) sacc[i][j] += a4[i] * b4[j];
        }
#pragma unroll
        for (int i = 0; i < 4; i++)
#pragma unroll
            for (int j = 0; j < 4; j++)
                Ss[ty * 4 + i][tx * 4 + j] = sacc[i][j] * SCc;
        __syncthreads();
        // ---- online softmax: pass 1, per-row tile max (4 threads/row) ----
        {
            int r = t >> 2, s0 = (t & 3) * 16;
            float mx = -1e30f;
#pragma unroll
            for (int j = 0; j < 16; j++) mx = fmaxf(mx, Ss[r][s0 + j]);
            pm[r][t & 3] = mx;
        }
        __syncthreads();
        if (t < 64) {
            float tm = fmaxf(fmaxf(pm[t][0], pm[t][1]), fmaxf(pm[t][2], pm[t][3]));
            float nm = fmaxf(mrow[t], tm);
            arow[t] = __expf(mrow[t] - nm);
            mrow[t] = nm;
        }
        __syncthreads();
        // ---- pass 2: exponentiate in place + partial sums ----
        {
            int r = t >> 2, s0 = (t & 3) * 16;
            float nm = mrow[r];
            float sm = 0.f;
#pragma unroll
            for (int j = 0; j < 16; j++) {
                float p = __expf(Ss[r][s0 + j] - nm);
                Ss[r][s0 + j] = p;
                sm += p;
            }
            ps[r][t & 3] = sm;
        }
        __syncthreads();
        if (t < 64)
            lrow[t] = lrow[t] * arow[t] + ps[t][0] + ps[t][1] + ps[t][2] + ps[t][3];
        // ---- O[c][i] = alpha[i]*O + V P^T ----
        float al[4];
#pragma unroll
        for (int ii = 0; ii < 4; ii++) al[ii] = arow[tx * 4 + ii];
#pragma unroll
        for (int cc = 0; cc < 4; cc++)
#pragma unroll
            for (int ii = 0; ii < 4; ii++) oacc[cc][ii] *= al[ii];
#pragma unroll 8
        for (int j = 0; j < 64; j++) {
            float4 vv = *(const float4*)&Vt[j][ty * 4];
            float v4[4] = {vv.x, vv.y, vv.z, vv.w};
            float p4[4];
#pragma unroll
            for (int ii = 0; ii < 4; ii++) p4[ii] = Ss[tx * 4 + ii][j];
#pragma unroll
            for (int cc = 0; cc < 4; cc++)
#pragma unroll
                for (int ii = 0; ii < 4; ii++) oacc[cc][ii] += v4[cc] * p4[ii];
        }
    }
    __syncthreads();
#pragma unroll
    for (int cc = 0; cc < 4; cc++) {
        int ch = h * 64 + ty * 4 + cc;
        float4 r4;
        r4.x = oacc[cc][0] / lrow[tx * 4 + 0];
        r4.y = oacc[cc][1] / lrow[tx * 4 + 1];
        r4.z = oacc[cc][2] / lrow[tx * 4 + 2];
        r4.w = oacc[cc][3] / lrow[tx * 4 + 3];
        *(float4*)&ob[((size_t)(b * Cch + ch)) * Nc + i0 + tx * 4] = r4;
    }
}

// ---------------------------------------------------------------------------
// Kernel 4: out = x + p_w (256x256) @ o (256x1024) + p_b, per batch.
// Grid: (n_tiles=16, m_tiles=4, B=16).
// ---------------------------------------------------------------------------
__global__ __launch_bounds__(256) void proj_gemm_k(
    const float* __restrict__ ob, const float* __restrict__ w,
    const float* __restrict__ wb, const float* __restrict__ x,
    float* __restrict__ out) {
    int b  = blockIdx.z;
    int m0 = blockIdx.y * 64;
    int n0 = blockIdx.x * 64;
    __shared__ __align__(16) float As[64][68]; // [k][m]
    __shared__ __align__(16) float Bs[64][68]; // [k][n]
    int t = threadIdx.x, ty = t >> 4, tx = t & 15;
    float acc[4][4] = {};
    for (int k0 = 0; k0 < 256; k0 += 64) {
        __syncthreads();
#pragma unroll
        for (int r = 0; r < 16; r++) {
            int e = t + r * 256;
            int k = e & 63, m = e >> 6;
            As[k][m] = w[(m0 + m) * 256 + k0 + k];
        }
#pragma unroll
        for (int r = 0; r < 16; r++) {
            int e = t + r * 256;
            int n = e & 63, k = e >> 6;
            Bs[k][n] = ob[((size_t)(b * Cch + k0 + k)) * Nc + n0 + n];
        }
        __syncthreads();
#pragma unroll 16
        for (int k = 0; k < 64; k++) {
            float4 av = *(const float4*)&As[k][ty * 4];
            float4 bv = *(const float4*)&Bs[k][tx * 4];
            float a4[4] = {av.x, av.y, av.z, av.w};
            float b4[4] = {bv.x, bv.y, bv.z, bv.w};
#pragma unroll
            for (int i = 0; i < 4; i++)
#pragma unroll
                for (int j = 0; j < 4; j++) acc[i][j] += a4[i] * b4[j];
        }
    }
#pragma unroll
    for (int i = 0; i < 4; i++) {
        int m = m0 + ty * 4 + i;
        float bb = wb[m];
        const float4 xr = *(const float4*)&x[((size_t)(b * Cch + m)) * Nc + n0 + tx * 4];
        float4 r4;
        r4.x = acc[i][0] + bb + xr.x;
        r4.y = acc[i][1] + bb + xr.y;
        r4.z = acc[i][2] + bb + xr.z;
        r4.w = acc[i][3] + bb + xr.w;
        *(float4*)&out[((size_t)(b * Cch + m)) * Nc + n0 + tx * 4] = r4;
    }
}

// ---------------------------------------------------------------------------
extern "C" void kernel_launch(void* const* d_in, const int* in_sizes, int n_in,
                              void* d_out, int out_size, void* d_ws, size_t ws_size,
                              hipStream_t stream) {
    const float* x    = (const float*)d_in[0];
    const float* nw   = (const float*)d_in[1];
    const float* nb   = (const float*)d_in[2];
    const float* qkvw = (const float*)d_in[3];
    const float* qkvb = (const float*)d_in[4];
    const float* pw   = (const float*)d_in[5];
    const float* pb   = (const float*)d_in[6];
    float* out = (float*)d_out;

    // Workspace layout (floats): stats[256] | qkv[16*768*1024] | obuf[16*256*1024]
    float* ws    = (float*)d_ws;
    float* stats = ws;
    float* qkv   = ws + 256;
    float* obuf  = qkv + (size_t)Bc * 768 * Nc;

    gn_stats_k<<<dim3(Bc * Gc), dim3(256), 0, stream>>>(x, stats);
    qkv_gemm_k<<<dim3(16, 12, Bc), dim3(256), 0, stream>>>(x, stats, nw, nb, qkvw, qkvb, qkv);
    attn_k<<<dim3(16, Bc * 4), dim3(256), 0, stream>>>(qkv, obuf);
    proj_gemm_k<<<dim3(16, 4, Bc), dim3(256), 0, stream>>>(obuf, pw, pb, x, out);
}

// Round 3
// 198.228 us; speedup vs baseline: 3.0088x; 3.0088x over previous
//
#include <hip/hip_runtime.h>
#include <math.h>

typedef unsigned short ushort;
typedef unsigned int uint;
typedef __attribute__((ext_vector_type(8))) short bf16x8;
typedef __attribute__((ext_vector_type(4))) float f32x4;

constexpr int Bc  = 16;
constexpr float EPSc = 1e-5f;
constexpr float SCc  = 0.125f; // dh^-0.5, dh=64

__device__ inline ushort f2bf(float f) {
    uint u = __float_as_uint(f);
    uint r = (u + 0x7fffu + ((u >> 16) & 1u)) >> 16;
    return (ushort)r;
}
__device__ inline uint pack2(float a, float b) {
    return (uint)f2bf(a) | ((uint)f2bf(b) << 16);
}

// ---------------------------------------------------------------------------
// K1: per-(b,g) mean / invstd.  Grid = 128 blocks.
// ---------------------------------------------------------------------------
__global__ __launch_bounds__(256) void gn_stats_k(const float* __restrict__ x,
                                                  float* __restrict__ stats) {
    int bg = blockIdx.x;
    const float4* p = (const float4*)(x + (size_t)bg * 32768);
    float s = 0.f, s2 = 0.f;
    for (int i = threadIdx.x; i < 8192; i += 256) {
        float4 v = p[i];
        s += v.x + v.y + v.z + v.w;
        s2 += v.x*v.x + v.y*v.y + v.z*v.z + v.w*v.w;
    }
    __shared__ float rs[256], rq[256];
    rs[threadIdx.x] = s; rq[threadIdx.x] = s2;
    __syncthreads();
    for (int off = 128; off > 0; off >>= 1) {
        if (threadIdx.x < (unsigned)off) {
            rs[threadIdx.x] += rs[threadIdx.x + off];
            rq[threadIdx.x] += rq[threadIdx.x + off];
        }
        __syncthreads();
    }
    if (threadIdx.x == 0) {
        float inv_n = 1.f / 32768.f;
        float mean = rs[0] * inv_n;
        float var  = rq[0] * inv_n - mean * mean;
        stats[bg * 2]     = mean;
        stats[bg * 2 + 1] = rsqrtf(var + EPSc);
    }
}

// ---------------------------------------------------------------------------
// K2: GroupNorm + cast + transpose: x[b][c][n] -> xt[b][n][c] bf16.
// Grid (16 n-tiles, 4 c-tiles, 16 b), 64x64 tile per block.
// ---------------------------------------------------------------------------
__global__ __launch_bounds__(256) void norm_t_k(
    const float* __restrict__ x, const float* __restrict__ stats,
    const float* __restrict__ nw, const float* __restrict__ nb,
    ushort* __restrict__ xt) {
    int b = blockIdx.z, ct = blockIdx.y, nt = blockIdx.x;
    __shared__ ushort T[64 * 72];
    int t = threadIdx.x;
    int nn4 = (t & 15) * 4;
#pragma unroll
    for (int p = 0; p < 4; ++p) {
        int cl = (t >> 4) + p * 16;
        int c = ct * 64 + cl;
        int g = c >> 5;
        float mean = stats[(b * 8 + g) * 2];
        float inv  = stats[(b * 8 + g) * 2 + 1];
        float sw = inv * nw[c];
        float sb = nb[c] - mean * sw;
        float4 v = *(const float4*)&x[((size_t)(b * 256 + c)) * 1024 + nt * 64 + nn4];
        T[(nn4 + 0) * 72 + cl] = f2bf(v.x * sw + sb);
        T[(nn4 + 1) * 72 + cl] = f2bf(v.y * sw + sb);
        T[(nn4 + 2) * 72 + cl] = f2bf(v.z * sw + sb);
        T[(nn4 + 3) * 72 + cl] = f2bf(v.w * sw + sb);
    }
    __syncthreads();
#pragma unroll
    for (int p = 0; p < 4; ++p) {
        int nn = (t >> 4) + p * 16;
        int c4 = (t & 15) * 4;
        uint2 w = *(const uint2*)&T[nn * 72 + c4];
        *(uint2*)&xt[((size_t)b * 1024 + nt * 64 + nn) * 256 + ct * 64 + c4] = w;
    }
}

// ---------------------------------------------------------------------------
// K3: convert weights to bf16 (natural [m][k] layout). 256 blocks.
// ---------------------------------------------------------------------------
__global__ __launch_bounds__(256) void wcvt_k(
    const float* __restrict__ qkvw, const float* __restrict__ pw,
    ushort* __restrict__ wqb, ushort* __restrict__ pwb) {
    int idx = (blockIdx.x * 256 + threadIdx.x) * 4;
    if (idx < 196608) {
        float4 v = *(const float4*)&qkvw[idx];
        uint2 u; u.x = pack2(v.x, v.y); u.y = pack2(v.z, v.w);
        *(uint2*)&wqb[idx] = u;
    } else {
        int j = idx - 196608;
        float4 v = *(const float4*)&pw[j];
        uint2 u; u.x = pack2(v.x, v.y); u.y = pack2(v.z, v.w);
        *(uint2*)&pwb[j] = u;
    }
}

// ---------------------------------------------------------------------------
// K4: qkv GEMM, bf16 MFMA. 128x128 tile, BK=64, 4 waves (2x2 of 64x64).
// chan-tiles 0..3 (Q,K): output TRANSPOSED qkT[b][sp][512] = D[sp][chan].
// chan-tiles 4..5 (V): output natural vbuf[b][chan][sp].
// ---------------------------------------------------------------------------
__global__ __launch_bounds__(256) void qkv_gemm_k(
    const ushort* __restrict__ wq, const ushort* __restrict__ xt,
    const float* __restrict__ wb, ushort* __restrict__ qkT,
    ushort* __restrict__ vbuf) {
    int b = blockIdx.z, cy = blockIdx.y, sx = blockIdx.x;
    __shared__ ushort Wt[128 * 72], Xt[128 * 72];
    int t = threadIdx.x, lane = t & 63, w = t >> 6;
    int quad = lane >> 4, l15 = lane & 15;
    int wm = w >> 1, wn = w & 1;
    const ushort* wrow = wq + (size_t)cy * 128 * 256;
    const ushort* xrow = xt + ((size_t)b * 1024 + sx * 128) * 256;
    bool tpath = (cy < 4);
    f32x4 acc[4][4] = {};
    for (int k0 = 0; k0 < 256; k0 += 64) {
        __syncthreads();
#pragma unroll
        for (int it = 0; it < 4; ++it) {
            int r = (t >> 3) + it * 32, ch = t & 7;
            *(uint4*)&Wt[r * 72 + ch * 8] = *(const uint4*)&wrow[(size_t)r * 256 + k0 + ch * 8];
            *(uint4*)&Xt[r * 72 + ch * 8] = *(const uint4*)&xrow[(size_t)r * 256 + k0 + ch * 8];
        }
        __syncthreads();
#pragma unroll
        for (int kk = 0; kk < 64; kk += 32) {
            bf16x8 fa[4], fb[4];
            if (tpath) {
#pragma unroll
                for (int mi = 0; mi < 4; ++mi)
                    fa[mi] = *(const bf16x8*)&Xt[(wm * 64 + mi * 16 + l15) * 72 + kk + quad * 8];
#pragma unroll
                for (int ni = 0; ni < 4; ++ni)
                    fb[ni] = *(const bf16x8*)&Wt[(wn * 64 + ni * 16 + l15) * 72 + kk + quad * 8];
            } else {
#pragma unroll
                for (int mi = 0; mi < 4; ++mi)
                    fa[mi] = *(const bf16x8*)&Wt[(wm * 64 + mi * 16 + l15) * 72 + kk + quad * 8];
#pragma unroll
                for (int ni = 0; ni < 4; ++ni)
                    fb[ni] = *(const bf16x8*)&Xt[(wn * 64 + ni * 16 + l15) * 72 + kk + quad * 8];
            }
#pragma unroll
            for (int mi = 0; mi < 4; ++mi)
#pragma unroll
                for (int ni = 0; ni < 4; ++ni)
                    acc[mi][ni] = __builtin_amdgcn_mfma_f32_16x16x32_bf16(
                        fa[mi], fb[ni], acc[mi][ni], 0, 0, 0);
        }
    }
    if (tpath) {
#pragma unroll
        for (int mi = 0; mi < 4; ++mi)
#pragma unroll
            for (int ni = 0; ni < 4; ++ni) {
                int chan = cy * 128 + wn * 64 + ni * 16 + l15;
                float bias = wb[chan];
#pragma unroll
                for (int rr = 0; rr < 4; ++rr) {
                    int sp = sx * 128 + wm * 64 + mi * 16 + quad * 4 + rr;
                    qkT[((size_t)b * 1024 + sp) * 512 + chan] = f2bf(acc[mi][ni][rr] + bias);
                }
            }
    } else {
#pragma unroll
        for (int mi = 0; mi < 4; ++mi)
#pragma unroll
            for (int rr = 0; rr < 4; ++rr) {
                int chan = cy * 128 + wm * 64 + mi * 16 + quad * 4 + rr;
                float bias = wb[chan];
                int chanloc = chan - 512;
#pragma unroll
                for (int ni = 0; ni < 4; ++ni) {
                    int sp = sx * 128 + wn * 64 + ni * 16 + l15;
                    vbuf[((size_t)b * 256 + chanloc) * 1024 + sp] = f2bf(acc[mi][ni][rr] + bias);
                }
            }
    }
}

// ---------------------------------------------------------------------------
// K5: flash attention, bf16 MFMA. Grid (16 i-tiles, 64 b*h), 4 waves.
// Wave w owns 16 query rows. P round-trips through LDS with an explicit
// __syncthreads() between write and read (hardened vs within-wave-order
// assumption). Output ot[b][i][256] bf16.
// ---------------------------------------------------------------------------
__global__ __launch_bounds__(256) void attn_k(
    const ushort* __restrict__ qkT, const ushort* __restrict__ vbuf,
    ushort* __restrict__ ot) {
    int i0 = blockIdx.x * 64;
    int bh = blockIdx.y;
    int b = bh >> 2, h = bh & 3;
    const ushort* qTb = qkT + (size_t)b * 1024 * 512 + h * 64;
    const ushort* kTb = qTb + 256;
    const ushort* vb  = vbuf + ((size_t)(b * 256 + h * 64)) * 1024;
    __shared__ ushort Qs[64 * 72], Ks[64 * 72], Vs[64 * 72], Ps[4 * 16 * 72];
    int t = threadIdx.x, lane = t & 63, w = t >> 6;
    int quad = lane >> 4, l15 = lane & 15;
#pragma unroll
    for (int it = 0; it < 2; ++it) {
        int r = (t >> 3) + it * 32, ch = t & 7;
        *(uint4*)&Qs[r * 72 + ch * 8] = *(const uint4*)&qTb[(size_t)(i0 + r) * 512 + ch * 8];
    }
    __syncthreads();
    bf16x8 aq0 = *(const bf16x8*)&Qs[(w * 16 + l15) * 72 + quad * 8];
    bf16x8 aq1 = *(const bf16x8*)&Qs[(w * 16 + l15) * 72 + 32 + quad * 8];
    float mr[4] = {-1e30f, -1e30f, -1e30f, -1e30f};
    float lr[4] = {0.f, 0.f, 0.f, 0.f};
    f32x4 oacc[4] = {};
    for (int j0 = 0; j0 < 1024; j0 += 64) {
        __syncthreads();
#pragma unroll
        for (int it = 0; it < 2; ++it) {
            int r = (t >> 3) + it * 32, ch = t & 7;
            *(uint4*)&Ks[r * 72 + ch * 8] = *(const uint4*)&kTb[(size_t)(j0 + r) * 512 + ch * 8];
            *(uint4*)&Vs[r * 72 + ch * 8] = *(const uint4*)&vb[(size_t)r * 1024 + j0 + ch * 8];
        }
        __syncthreads();
        f32x4 sacc[4];
#pragma unroll
        for (int jt = 0; jt < 4; ++jt) {
            f32x4 a = {0.f, 0.f, 0.f, 0.f};
            bf16x8 bk0 = *(const bf16x8*)&Ks[(jt * 16 + l15) * 72 + quad * 8];
            bf16x8 bk1 = *(const bf16x8*)&Ks[(jt * 16 + l15) * 72 + 32 + quad * 8];
            a = __builtin_amdgcn_mfma_f32_16x16x32_bf16(aq0, bk0, a, 0, 0, 0);
            a = __builtin_amdgcn_mfma_f32_16x16x32_bf16(aq1, bk1, a, 0, 0, 0);
            sacc[jt] = a;
        }
#pragma unroll
        for (int jt = 0; jt < 4; ++jt)
#pragma unroll
            for (int rr = 0; rr < 4; ++rr) sacc[jt][rr] *= SCc;
        float tm[4], al[4], rsum[4];
#pragma unroll
        for (int rr = 0; rr < 4; ++rr) {
            tm[rr] = fmaxf(fmaxf(sacc[0][rr], sacc[1][rr]), fmaxf(sacc[2][rr], sacc[3][rr]));
#pragma unroll
            for (int msk = 1; msk < 16; msk <<= 1)
                tm[rr] = fmaxf(tm[rr], __shfl_xor(tm[rr], msk));
            float nm = fmaxf(mr[rr], tm[rr]);
            al[rr] = __expf(mr[rr] - nm);
            mr[rr] = nm;
            rsum[rr] = 0.f;
        }
#pragma unroll
        for (int jt = 0; jt < 4; ++jt)
#pragma unroll
            for (int rr = 0; rr < 4; ++rr) {
                float p = __expf(sacc[jt][rr] - mr[rr]);
                Ps[w * 1152 + (quad * 4 + rr) * 72 + jt * 16 + l15] = f2bf(p);
                rsum[rr] += p;
            }
#pragma unroll
        for (int rr = 0; rr < 4; ++rr) {
#pragma unroll
            for (int msk = 1; msk < 16; msk <<= 1)
                rsum[rr] += __shfl_xor(rsum[rr], msk);
            lr[rr] = lr[rr] * al[rr] + rsum[rr];
        }
#pragma unroll
        for (int ct = 0; ct < 4; ++ct)
#pragma unroll
            for (int rr = 0; rr < 4; ++rr) oacc[ct][rr] *= al[rr];
        __syncthreads();  // guarantee Ps writes visible before A-fragment reads
        bf16x8 ap0 = *(const bf16x8*)&Ps[w * 1152 + l15 * 72 + quad * 8];
        bf16x8 ap1 = *(const bf16x8*)&Ps[w * 1152 + l15 * 72 + 32 + quad * 8];
#pragma unroll
        for (int ct = 0; ct < 4; ++ct) {
            bf16x8 bv0 = *(const bf16x8*)&Vs[(ct * 16 + l15) * 72 + quad * 8];
            bf16x8 bv1 = *(const bf16x8*)&Vs[(ct * 16 + l15) * 72 + 32 + quad * 8];
            oacc[ct] = __builtin_amdgcn_mfma_f32_16x16x32_bf16(ap0, bv0, oacc[ct], 0, 0, 0);
            oacc[ct] = __builtin_amdgcn_mfma_f32_16x16x32_bf16(ap1, bv1, oacc[ct], 0, 0, 0);
        }
    }
    float linv[4];
#pragma unroll
    for (int rr = 0; rr < 4; ++rr) linv[rr] = 1.f / lr[rr];
#pragma unroll
    for (int ct = 0; ct < 4; ++ct)
#pragma unroll
        for (int rr = 0; rr < 4; ++rr) {
            int i = i0 + w * 16 + quad * 4 + rr;
            int c = h * 64 + ct * 16 + l15;
            ot[((size_t)b * 1024 + i) * 256 + c] = f2bf(oacc[ct][rr] * linv[rr]);
        }
}

// ---------------------------------------------------------------------------
// K6: proj GEMM + bias + residual, fp32 out. Grid (8, 2, 16).
// ---------------------------------------------------------------------------
__global__ __launch_bounds__(256) void proj_k(
    const ushort* __restrict__ pwb, const ushort* __restrict__ ot,
    const float* __restrict__ pb, const float* __restrict__ x,
    float* __restrict__ out) {
    int b = blockIdx.z, cy = blockIdx.y, sx = blockIdx.x;
    __shared__ ushort Wt[128 * 72], Xt[128 * 72];
    int t = threadIdx.x, lane = t & 63, w = t >> 6;
    int quad = lane >> 4, l15 = lane & 15;
    int wm = w >> 1, wn = w & 1;
    const ushort* wrow = pwb + (size_t)cy * 128 * 256;
    const ushort* xrow = ot + ((size_t)b * 1024 + sx * 128) * 256;
    f32x4 acc[4][4] = {};
    for (int k0 = 0; k0 < 256; k0 += 64) {
        __syncthreads();
#pragma unroll
        for (int it = 0; it < 4; ++it) {
            int r = (t >> 3) + it * 32, ch = t & 7;
            *(uint4*)&Wt[r * 72 + ch * 8] = *(const uint4*)&wrow[(size_t)r * 256 + k0 + ch * 8];
            *(uint4*)&Xt[r * 72 + ch * 8] = *(const uint4*)&xrow[(size_t)r * 256 + k0 + ch * 8];
        }
        __syncthreads();
#pragma unroll
        for (int kk = 0; kk < 64; kk += 32) {
            bf16x8 fa[4], fb[4];
#pragma unroll
            for (int mi = 0; mi < 4; ++mi)
                fa[mi] = *(const bf16x8*)&Wt[(wm * 64 + mi * 16 + l15) * 72 + kk + quad * 8];
#pragma unroll
            for (int ni = 0; ni < 4; ++ni)
                fb[ni] = *(const bf16x8*)&Xt[(wn * 64 + ni * 16 + l15) * 72 + kk + quad * 8];
#pragma unroll
            for (int mi = 0; mi < 4; ++mi)
#pragma unroll
                for (int ni = 0; ni < 4; ++ni)
                    acc[mi][ni] = __builtin_amdgcn_mfma_f32_16x16x32_bf16(
                        fa[mi], fb[ni], acc[mi][ni], 0, 0, 0);
        }
    }
#pragma unroll
    for (int mi = 0; mi < 4; ++mi)
#pragma unroll
        for (int rr = 0; rr < 4; ++rr) {
            int chan = cy * 128 + wm * 64 + mi * 16 + quad * 4 + rr;
            float bias = pb[chan];
#pragma unroll
            for (int ni = 0; ni < 4; ++ni) {
                int sp = sx * 128 + wn * 64 + ni * 16 + l15;
                size_t o = ((size_t)(b * 256 + chan)) * 1024 + sp;
                out[o] = acc[mi][ni][rr] + bias + x[o];
            }
        }
}

// ---------------------------------------------------------------------------
extern "C" void kernel_launch(void* const* d_in, const int* in_sizes, int n_in,
                              void* d_out, int out_size, void* d_ws, size_t ws_size,
                              hipStream_t stream) {
    const float* x    = (const float*)d_in[0];
    const float* nw   = (const float*)d_in[1];
    const float* nb   = (const float*)d_in[2];
    const float* qkvw = (const float*)d_in[3];
    const float* qkvb = (const float*)d_in[4];
    const float* pw   = (const float*)d_in[5];
    const float* pb   = (const float*)d_in[6];
    float* out = (float*)d_out;

    // Workspace: stats(256 f32) | xt | wqb | pwb | qkT | vbuf  (bf16/ushort)
    // ot ALIASES xt: xt's last reader (qkv_gemm_k) precedes ot's first
    // writer (attn_k) in stream order.  Total ~34 MB.
    float* stats = (float*)d_ws;
    ushort* base = (ushort*)((char*)d_ws + 1024);
    ushort* xt   = base;                          // 16*1024*256
    ushort* wqb  = xt + (size_t)16 * 1024 * 256;  // 768*256
    ushort* pwb  = wqb + 768 * 256;               // 256*256
    ushort* qkT  = pwb + 256 * 256;               // 16*1024*512
    ushort* vbuf = qkT + (size_t)16 * 1024 * 512; // 16*256*1024
    ushort* ot   = xt;                            // reuse

    gn_stats_k<<<dim3(128), dim3(256), 0, stream>>>(x, stats);
    norm_t_k<<<dim3(16, 4, Bc), dim3(256), 0, stream>>>(x, stats, nw, nb, xt);
    wcvt_k<<<dim3(256), dim3(256), 0, stream>>>(qkvw, pw, wqb, pwb);
    qkv_gemm_k<<<dim3(8, 6, Bc), dim3(256), 0, stream>>>(wqb, xt, qkvb, qkT, vbuf);
    attn_k<<<dim3(16, 64), dim3(256), 0, stream>>>(qkT, vbuf, ot);
    proj_k<<<dim3(8, 2, Bc), dim3(256), 0, stream>>>(pwb, ot, pb, x, out);
}